// Round 6
// baseline (733.366 us; speedup 1.0000x reference)
//
#include <hip/hip_runtime.h>
#include <cstdint>
#include <cstddef>

#define NAG 32
#define N1C 32
#define N2C 496
#define NF 528
#define HD 64
#define SD 512

typedef __attribute__((ext_vector_type(8))) short bf16x8;
typedef __attribute__((ext_vector_type(4))) float f32x4;
#define MFMA16(a, b, c) __builtin_amdgcn_mfma_f32_16x16x32_bf16(a, b, c, 0, 0, 0)

__device__ __forceinline__ unsigned short f2bf(float f) {
    unsigned int u = __float_as_uint(f);
    u += 0x7fffu + ((u >> 16) & 1u);
    return (unsigned short)(u >> 16);
}
__device__ __forceinline__ unsigned int pack2(float a, float b) {
    return (unsigned int)f2bf(a) | ((unsigned int)f2bf(b) << 16);
}
__device__ __forceinline__ float elu_f(float x) {
    return x > 0.f ? x : (__expf(x) - 1.f);
}

// ---- d_ws layout: ushort/bf16 region [wsT[64][512], wb1T[64][512], wzT[64][512],
//      wa1T[64][128], wa2T[528][64]] followed by f32 region wf[528][68]
//      (per-function shape-MLP pack, |w| pre-applied, pi/pj embedded).
#define OFF_WST   0
#define OFF_WB1T  32768
#define OFF_WZT   65536
#define OFF_WA1T  98304
#define OFF_WA2T  106496
#define PREP_TOT  140288
#define WFS       68

// ---------------- Kernel 0: weight transpose/convert + shape-MLP pack ----------------
__global__ __launch_bounds__(256) void prep_kernel(
    const float* __restrict__ ws_w, const float* __restrict__ wb1_w,
    const float* __restrict__ wz_w, const float* __restrict__ wa1_w,
    const float* __restrict__ wa2_w,
    const float* __restrict__ w1_1, const float* __restrict__ b1_1,
    const float* __restrict__ w2_1, const float* __restrict__ b2_1,
    const float* __restrict__ w3_1, const float* __restrict__ b3_1,
    const float* __restrict__ w1_2, const float* __restrict__ b1_2,
    const float* __restrict__ w2_2, const float* __restrict__ b2_2,
    const float* __restrict__ w3_2, const float* __restrict__ b3_2,
    unsigned short* __restrict__ ws)
{
    int i = blockIdx.x * 256 + threadIdx.x;
    if (i < PREP_TOT) {
        float v;
        if (i < OFF_WB1T) {
            int j = i - OFF_WST; int n = j >> 9, k = j & 511;
            v = ws_w[k * 64 + n];
        } else if (i < OFF_WZT) {
            int j = i - OFF_WB1T; int n = j >> 9, k = j & 511;
            v = wb1_w[k * 64 + n];
        } else if (i < OFF_WA1T) {
            int j = i - OFF_WZT; int n = j >> 9, k = j & 511;
            v = wz_w[k * 64 + n];
        } else if (i < OFF_WA2T) {
            int j = i - OFF_WA1T; int n = j >> 7, k = j & 127;
            v = wa1_w[k * 64 + n];
        } else {
            int j = i - OFF_WA2T; int n = j >> 6, k = j & 63;
            v = wa2_w[k * NF + n];
        }
        ws[i] = f2bf(v);
        return;
    }
    int f = i - PREP_TOT;
    if (f >= NF) return;
    float* wf = (float*)(ws + PREP_TOT) + (size_t)f * WFS;
    int pi, pj;
    if (f < N1C) {
        int n = f; pi = n; pj = n;
        for (int k = 0; k < 8; k++) { wf[k] = fabsf(w1_1[n*8+k]); wf[8+k] = 0.f; wf[16+k] = b1_1[n*8+k]; }
        for (int t = 0; t < 32; t++) wf[24+t] = fabsf(w2_1[n*32+t]);
        for (int j = 0; j < 4; j++) { wf[56+j] = b2_1[n*4+j]; wf[60+j] = fabsf(w3_1[n*4+j]); }
        wf[64] = b3_1[n];
    } else {
        int n = f - N1C;
        int p = n, ii = 0, c = NAG - 1;
        while (p >= c) { p -= c; c--; ii++; }
        pi = ii; pj = ii + 1 + p;
        for (int k = 0; k < 8; k++) { wf[k] = fabsf(w1_2[n*16+k]); wf[8+k] = fabsf(w1_2[n*16+8+k]); wf[16+k] = b1_2[n*8+k]; }
        for (int t = 0; t < 32; t++) wf[24+t] = fabsf(w2_2[n*32+t]);
        for (int j = 0; j < 4; j++) { wf[56+j] = b2_2[n*4+j]; wf[60+j] = fabsf(w3_2[n*4+j]); }
        wf[64] = b3_2[n];
    }
    wf[65] = __int_as_float(pi);
    wf[66] = __int_as_float(pj);
    wf[67] = 0.f;
}

// ---------------- Kernel 1: fused zero-barrier MFMA encoder + shape MLP ----------------
// Evidence R0/R2/R4/R5: enc's memory timeline pinned ~121us with all pipes ~90% idle;
// shape_kernel ran SERIALLY before it plus a 69MB shape round-trip. Fused: pass 1
// computes each shape value on the fly (lane already owns (row,f)), writes shape_out
// once, feeds weighted-sum from registers. Shape VALU fills enc's idle slots; the
// separate dispatch + round-trip vanish. Wave-private everything -> zero barriers.
#define RB 64
#define KH 256
#define SAP 264   // KH + 8 shorts pad

__global__ __launch_bounds__(256, 2) void enc_mfma(
    const float* __restrict__ q,
    const float* __restrict__ state,
    const float* __restrict__ sem,
    const unsigned short* __restrict__ wsbuf,
    const float* __restrict__ wfbuf,
    const float* __restrict__ ws_b, const float* __restrict__ wz_b,
    const float* __restrict__ wa1_b, const float* __restrict__ wa2_b,
    const float* __restrict__ wb1_b, const float* __restrict__ wb2_w,
    const float* __restrict__ wb2_b,
    float* __restrict__ shape_out,
    float* __restrict__ q_total,
    float* __restrict__ attn_out)
{
    __shared__ unsigned short sA[RB][SAP];    // staged A half-tile (bf16)
    __shared__ unsigned short sComb[RB][136]; // [relu(C1)|relu(C3)], padded
    __shared__ unsigned short sH[RB][72];     // relu(C4), padded
    __shared__ float qs[RB][36];              // q tile f32 (pad 36: quad rows hit distinct banks)

    const unsigned short* wsT  = wsbuf + OFF_WST;
    const unsigned short* wb1T = wsbuf + OFF_WB1T;
    const unsigned short* wzT  = wsbuf + OFF_WZT;
    const unsigned short* wa1T = wsbuf + OFF_WA1T;
    const unsigned short* wa2T = wsbuf + OFF_WA2T;

    int tid  = threadIdx.x;
    int lane = tid & 63;
    int w    = tid >> 6;
    int col  = lane & 15;
    int quad = lane >> 4;
    int r0   = blockIdx.x * RB;
    int rowt = w * 16;

    // ---- stage own 16 rows of q (wave-private, 2KB contiguous) ----
    #pragma unroll
    for (int b = 0; b < 2; b++) {
        int idx = b * 64 + lane;      // 0..127
        int qr  = idx >> 3;           // 0..15
        int qc  = (idx & 7) * 4;
        float4 v = *(const float4*)&q[(size_t)(r0 + rowt + qr) * NAG + qc];
        qs[rowt + qr][qc + 0] = v.x; qs[rowt + qr][qc + 1] = v.y;
        qs[rowt + qr][qc + 2] = v.z; qs[rowt + qr][qc + 3] = v.w;
    }

    const unsigned short* bS0 = wsT  + col * SD + quad * 8;
    const unsigned short* bB0 = wb1T + col * SD + quad * 8;
    const unsigned short* bZ0 = wzT  + col * SD + quad * 8;

    f32x4 accS[4], accB[4], accZ[4];
    #pragma unroll
    for (int ct = 0; ct < 4; ct++) {
        accS[ct] = (f32x4){0.f,0.f,0.f,0.f};
        accB[ct] = (f32x4){0.f,0.f,0.f,0.f};
        accZ[ct] = (f32x4){0.f,0.f,0.f,0.f};
    }

    // ---- state -> accS (ws), accB (wb1): two K-halves, wave-private staging ----
    #pragma unroll 1
    for (int h = 0; h < 2; h++) {
        int c0 = h * KH;
        #pragma unroll
        for (int b = 0; b < 4; b++) {
            float4 v[4];
            #pragma unroll
            for (int i = 0; i < 4; i++)
                v[i] = *(const float4*)&state[(size_t)(r0 + rowt + b*4 + i) * SD + c0 + lane * 4];
            #pragma unroll
            for (int i = 0; i < 4; i++) {
                uint2 p; p.x = pack2(v[i].x, v[i].y); p.y = pack2(v[i].z, v[i].w);
                *(uint2*)&sA[rowt + b*4 + i][lane * 4] = p;
            }
        }
        #pragma unroll
        for (int ks = 0; ks < 8; ks++) {
            bf16x8 a = *(const bf16x8*)&sA[rowt + col][ks * 32 + quad * 8];
            int wof = c0 + ks * 32;
            #pragma unroll
            for (int ct = 0; ct < 4; ct++) {
                bf16x8 bS = *(const bf16x8*)(bS0 + ct * 16 * SD + wof);
                bf16x8 bB = *(const bf16x8*)(bB0 + ct * 16 * SD + wof);
                accS[ct] = MFMA16(a, bS, accS[ct]);
                accB[ct] = MFMA16(a, bB, accB[ct]);
            }
        }
    }

    // ---- sem -> accZ (wz) ----
    #pragma unroll 1
    for (int h = 0; h < 2; h++) {
        int c0 = h * KH;
        #pragma unroll
        for (int b = 0; b < 4; b++) {
            float4 v[4];
            #pragma unroll
            for (int i = 0; i < 4; i++)
                v[i] = *(const float4*)&sem[(size_t)(r0 + rowt + b*4 + i) * SD + c0 + lane * 4];
            #pragma unroll
            for (int i = 0; i < 4; i++) {
                uint2 p; p.x = pack2(v[i].x, v[i].y); p.y = pack2(v[i].z, v[i].w);
                *(uint2*)&sA[rowt + b*4 + i][lane * 4] = p;
            }
        }
        #pragma unroll
        for (int ks = 0; ks < 8; ks++) {
            bf16x8 a = *(const bf16x8*)&sA[rowt + col][ks * 32 + quad * 8];
            int wof = c0 + ks * 32;
            #pragma unroll
            for (int ct = 0; ct < 4; ct++) {
                bf16x8 bZ = *(const bf16x8*)(bZ0 + ct * 16 * SD + wof);
                accZ[ct] = MFMA16(a, bZ, accZ[ct]);
            }
        }
    }

    // ---- comb = [relu(C1+ws_b) | relu(C3+wz_b)] (own rows -> no barrier) ----
    #pragma unroll
    for (int ct = 0; ct < 4; ct++) {
        float bs = ws_b[ct * 16 + col];
        float bz = wz_b[ct * 16 + col];
        #pragma unroll
        for (int reg = 0; reg < 4; reg++) {
            int rr = rowt + quad * 4 + reg;
            sComb[rr][ct * 16 + col]      = f2bf(fmaxf(accS[ct][reg] + bs, 0.f));
            sComb[rr][64 + ct * 16 + col] = f2bf(fmaxf(accZ[ct][reg] + bz, 0.f));
        }
    }

    // ---- bias head: qb = relu(C2+wb1_b) @ wb2_w ----
    float qbv[4];
    #pragma unroll
    for (int reg = 0; reg < 4; reg++) {
        float p = 0.f;
        #pragma unroll
        for (int ct = 0; ct < 4; ct++)
            p += fmaxf(accB[ct][reg] + wb1_b[ct * 16 + col], 0.f) * wb2_w[ct * 16 + col];
        #pragma unroll
        for (int m = 1; m < 16; m <<= 1) p += __shfl_xor(p, m, 64);
        qbv[reg] = p;
    }

    // ---- C4 = comb @ wa1 (own rows) ----
    f32x4 accH[4];
    #pragma unroll
    for (int ct = 0; ct < 4; ct++) accH[ct] = (f32x4){0.f,0.f,0.f,0.f};
    #pragma unroll
    for (int ks = 0; ks < 4; ks++) {
        bf16x8 a = *(const bf16x8*)&sComb[rowt + col][ks * 32 + quad * 8];
        #pragma unroll
        for (int ct = 0; ct < 4; ct++) {
            bf16x8 b = *(const bf16x8*)&wa1T[(ct * 16 + col) * 128 + ks * 32 + quad * 8];
            accH[ct] = MFMA16(a, b, accH[ct]);
        }
    }
    #pragma unroll
    for (int ct = 0; ct < 4; ct++) {
        float bh = wa1_b[ct * 16 + col];
        #pragma unroll
        for (int reg = 0; reg < 4; reg++)
            sH[rowt + quad * 4 + reg][ct * 16 + col] = f2bf(fmaxf(accH[ct][reg] + bh, 0.f));
    }

    bf16x8 ha0 = *(const bf16x8*)&sH[rowt + col][quad * 8];
    bf16x8 ha1 = *(const bf16x8*)&sH[rowt + col][32 + quad * 8];

    // ---- pass 1: logits + ON-THE-FLY shape values; denom + weighted sum ----
    float sAcc[4] = {0.f,0.f,0.f,0.f};
    float wAcc[4] = {0.f,0.f,0.f,0.f};
    #pragma unroll 1
    for (int nt = 0; nt < 33; nt++) {
        f32x4 acc = (f32x4){0.f,0.f,0.f,0.f};
        const unsigned short* wp = &wa2T[(nt * 16 + col) * 64 + quad * 8];
        acc = MFMA16(ha0, *(const bf16x8*)wp, acc);
        acc = MFMA16(ha1, *(const bf16x8*)(wp + 32), acc);
        float lb = wa2_b[nt * 16 + col];

        const float* wf = wfbuf + (size_t)(nt * 16 + col) * WFS;
        int pi = __float_as_int(wf[65]);
        int pj = __float_as_int(wf[66]);
        #pragma unroll
        for (int reg = 0; reg < 4; reg++) {
            int rr = rowt + quad * 4 + reg;
            float qi = qs[rr][pi];
            float qj = qs[rr][pj];
            float h1[8];
            #pragma unroll
            for (int k = 0; k < 8; k++)
                h1[k] = elu_f(wf[k] * qi + wf[8 + k] * qj + wf[16 + k]);
            float h2[4];
            #pragma unroll
            for (int j = 0; j < 4; j++) {
                float a = wf[56 + j];
                #pragma unroll
                for (int k = 0; k < 8; k++) a += h1[k] * wf[24 + k * 4 + j];
                h2[j] = elu_f(a);
            }
            float fv = wf[64];
            #pragma unroll
            for (int j = 0; j < 4; j++) fv += h2[j] * wf[60 + j];
            shape_out[(size_t)(r0 + rr) * NF + nt * 16 + col] = fv;
            float e = __expf(acc[reg] + lb);
            sAcc[reg] += e;
            wAcc[reg] += e * fv;
        }
    }
    float inv[4];
    #pragma unroll
    for (int reg = 0; reg < 4; reg++) {
        float s = sAcc[reg], ww = wAcc[reg];
        #pragma unroll
        for (int m = 1; m < 16; m <<= 1) { s += __shfl_xor(s, m, 64); ww += __shfl_xor(ww, m, 64); }
        inv[reg] = 1.f / s;
        if (col == 0)
            q_total[r0 + rowt + quad * 4 + reg] = ww * inv[reg] + qbv[reg] + wb2_b[0];
    }

    // ---- pass 2: recompute logits, write normalized attention ----
    for (int nt = 0; nt < 33; nt++) {
        f32x4 acc = (f32x4){0.f,0.f,0.f,0.f};
        const unsigned short* wp = &wa2T[(nt * 16 + col) * 64 + quad * 8];
        acc = MFMA16(ha0, *(const bf16x8*)wp, acc);
        acc = MFMA16(ha1, *(const bf16x8*)(wp + 32), acc);
        float lb = wa2_b[nt * 16 + col];
        #pragma unroll
        for (int reg = 0; reg < 4; reg++) {
            float e = __expf(acc[reg] + lb);
            attn_out[(size_t)(r0 + rowt + quad * 4 + reg) * NF + nt * 16 + col] = e * inv[reg];
        }
    }
}

extern "C" void kernel_launch(void* const* d_in, const int* in_sizes, int n_in,
                              void* d_out, int out_size, void* d_ws, size_t ws_size,
                              hipStream_t stream) {
    const float* q     = (const float*)d_in[0];
    const float* state = (const float*)d_in[1];
    const float* sem   = (const float*)d_in[2];
    const float* w1_1  = (const float*)d_in[3];
    const float* b1_1  = (const float*)d_in[4];
    const float* w2_1  = (const float*)d_in[5];
    const float* b2_1  = (const float*)d_in[6];
    const float* w3_1  = (const float*)d_in[7];
    const float* b3_1  = (const float*)d_in[8];
    const float* w1_2  = (const float*)d_in[9];
    const float* b1_2  = (const float*)d_in[10];
    const float* w2_2  = (const float*)d_in[11];
    const float* b2_2  = (const float*)d_in[12];
    const float* w3_2  = (const float*)d_in[13];
    const float* b3_2  = (const float*)d_in[14];
    const float* ws_w  = (const float*)d_in[15];
    const float* ws_b  = (const float*)d_in[16];
    const float* wz_w  = (const float*)d_in[17];
    const float* wz_b  = (const float*)d_in[18];
    const float* wa1_w = (const float*)d_in[19];
    const float* wa1_b = (const float*)d_in[20];
    const float* wa2_w = (const float*)d_in[21];
    const float* wa2_b = (const float*)d_in[22];
    const float* wb1_w = (const float*)d_in[23];
    const float* wb1_b = (const float*)d_in[24];
    const float* wb2_w = (const float*)d_in[25];
    const float* wb2_b = (const float*)d_in[26];

    int B = in_sizes[0] / NAG;

    float* out_q    = (float*)d_out;                 // [B]
    float* out_attn = out_q + B;                     // [B, NF]
    float* out_shp  = out_attn + (size_t)B * NF;     // [B, NF]

    unsigned short* wsbuf = (unsigned short*)d_ws;
    const float* wfbuf = (const float*)(wsbuf + PREP_TOT);

    prep_kernel<<<(PREP_TOT + NF + 255) / 256, 256, 0, stream>>>(
        ws_w, wb1_w, wz_w, wa1_w, wa2_w,
        w1_1, b1_1, w2_1, b2_1, w3_1, b3_1,
        w1_2, b1_2, w2_2, b2_2, w3_2, b3_2,
        wsbuf);

    enc_mfma<<<B / RB, 256, 0, stream>>>(q, state, sem, wsbuf, wfbuf,
        ws_b, wz_b, wa1_b, wa2_b, wb1_b, wb2_w, wb2_b,
        out_shp, out_q, out_attn);
}

// Round 7
// 374.302 us; speedup vs baseline: 1.9593x; 1.9593x over previous
//
#include <hip/hip_runtime.h>
#include <cstdint>
#include <cstddef>

#define NAG 32
#define N1C 32
#define N2C 496
#define NF 528
#define HD 64
#define SD 512

typedef __attribute__((ext_vector_type(8))) short bf16x8;
typedef __attribute__((ext_vector_type(4))) float f32x4;
#define MFMA16(a, b, c) __builtin_amdgcn_mfma_f32_16x16x32_bf16(a, b, c, 0, 0, 0)

__device__ __forceinline__ unsigned short f2bf(float f) {
    unsigned int u = __float_as_uint(f);
    u += 0x7fffu + ((u >> 16) & 1u);
    return (unsigned short)(u >> 16);
}
__device__ __forceinline__ unsigned int pack2(float a, float b) {
    return (unsigned int)f2bf(a) | ((unsigned int)f2bf(b) << 16);
}
__device__ __forceinline__ float elu_f(float x) {
    return x > 0.f ? x : (__expf(x) - 1.f);
}

// ---- d_ws layout (ushort/bf16), ALL FRAGMENT-PACKED so each MFMA B-operand
// load is ONE contiguous 1KB block per wave (16x fewer L1 transactions):
//   wsF / wb1F / wzF: [ks(16)][ct(4)][lane(64)][8]  (32768 each)
//   wa1F:             [ks(4)][ct(4)][lane(64)][8]   (8192)
//   wa2F:             [nt(33)][half(2)][lane(64)][8] (33792)
// frag value = W[k][n] with n = ct*16 + (lane&15), k = ks*32 + (lane>>4)*8 + j
#define OFF_WST   0
#define OFF_WB1T  32768
#define OFF_WZT   65536
#define OFF_WA1T  98304
#define OFF_WA2T  106496
#define PREP_TOT  140288

// ---------------- Kernel 0: weight fragment-pack + bf16 convert ----------------
__global__ __launch_bounds__(256) void prep_kernel(
    const float* __restrict__ ws_w, const float* __restrict__ wb1_w,
    const float* __restrict__ wz_w, const float* __restrict__ wa1_w,
    const float* __restrict__ wa2_w, unsigned short* __restrict__ ws)
{
    int i = blockIdx.x * 256 + threadIdx.x;
    if (i >= PREP_TOT) return;
    float v;
    if (i < OFF_WA1T) {
        int region = i >> 15;            // 0=ws, 1=wb1, 2=wz
        int j = i & 32767;
        int e = j & 7, lane = (j >> 3) & 63, ct = (j >> 9) & 3, ks = j >> 11;
        int n = ct * 16 + (lane & 15);
        int k = ks * 32 + (lane >> 4) * 8 + e;
        const float* src = region == 0 ? ws_w : (region == 1 ? wb1_w : wz_w);
        v = src[k * 64 + n];
    } else if (i < OFF_WA2T) {
        int j = i - OFF_WA1T;
        int e = j & 7, lane = (j >> 3) & 63, ct = (j >> 9) & 3, ks = j >> 11;  // ks 0..3
        int n = ct * 16 + (lane & 15);
        int k = ks * 32 + (lane >> 4) * 8 + e;   // 0..127
        v = wa1_w[k * 64 + n];
    } else {
        int j = i - OFF_WA2T;
        int e = j & 7, lane = (j >> 3) & 63, hh = (j >> 9) & 1, nt = j >> 10;  // nt 0..32
        int n = nt * 16 + (lane & 15);
        int k = hh * 32 + (lane >> 4) * 8 + e;   // 0..63
        v = wa2_w[k * NF + n];
    }
    ws[i] = f2bf(v);
}

// ---------------- Kernel 1: shape functions (proven R0/R5 version) ----------------
#define SROWS 64
__global__ __launch_bounds__(576) void shape_kernel(
    const float* __restrict__ q,
    const float* __restrict__ w1_1, const float* __restrict__ b1_1,
    const float* __restrict__ w2_1, const float* __restrict__ b2_1,
    const float* __restrict__ w3_1, const float* __restrict__ b3_1,
    const float* __restrict__ w1_2, const float* __restrict__ b1_2,
    const float* __restrict__ w2_2, const float* __restrict__ b2_2,
    const float* __restrict__ w3_2, const float* __restrict__ b3_2,
    float* __restrict__ shape_out, int B)
{
    __shared__ float qs[SROWS][NAG];

    int tid = threadIdx.x;
    int f = tid;
    bool valid = f < NF;
    int fe = valid ? f : (NF - 1);

    float w1a[8], w1b[8], b1v[8], w2v[32], b2v[4], w3v[4], b3v;
    int pi, pj;
    if (fe < N1C) {
        int n = fe;
        pi = n; pj = n;
        #pragma unroll
        for (int k = 0; k < 8; k++) { w1a[k] = fabsf(w1_1[n*8+k]); w1b[k] = 0.f; b1v[k] = b1_1[n*8+k]; }
        #pragma unroll
        for (int t = 0; t < 32; t++) w2v[t] = fabsf(w2_1[n*32+t]);
        #pragma unroll
        for (int j = 0; j < 4; j++) { b2v[j] = b2_1[n*4+j]; w3v[j] = fabsf(w3_1[n*4+j]); }
        b3v = b3_1[n];
    } else {
        int n = fe - N1C;
        int p = n, i = 0, c = NAG - 1;
        while (p >= c) { p -= c; c--; i++; }
        pi = i; pj = i + 1 + p;
        #pragma unroll
        for (int k = 0; k < 8; k++) { w1a[k] = fabsf(w1_2[n*16+k]); w1b[k] = fabsf(w1_2[n*16+8+k]); b1v[k] = b1_2[n*8+k]; }
        #pragma unroll
        for (int t = 0; t < 32; t++) w2v[t] = fabsf(w2_2[n*32+t]);
        #pragma unroll
        for (int j = 0; j < 4; j++) { b2v[j] = b2_2[n*4+j]; w3v[j] = fabsf(w3_2[n*4+j]); }
        b3v = b3_2[n];
    }

    int row0 = blockIdx.x * SROWS;
    if (tid < 512) {
        float4 v = *(const float4*)&q[(size_t)row0 * NAG + tid * 4];
        *(float4*)&((float*)qs)[tid * 4] = v;
    }
    __syncthreads();

    #pragma unroll 4
    for (int rr = 0; rr < SROWS; rr++) {
        float qi = qs[rr][pi];
        float qj = qs[rr][pj];
        float h1[8];
        #pragma unroll
        for (int k = 0; k < 8; k++) h1[k] = elu_f(w1a[k]*qi + w1b[k]*qj + b1v[k]);
        float h2[4];
        #pragma unroll
        for (int j = 0; j < 4; j++) {
            float a = b2v[j];
            #pragma unroll
            for (int k = 0; k < 8; k++) a += h1[k] * w2v[k*4 + j];
            h2[j] = elu_f(a);
        }
        float fv = b3v;
        #pragma unroll
        for (int j = 0; j < 4; j++) fv += h2[j] * w3v[j];
        if (valid) shape_out[(size_t)(row0 + rr) * NF + f] = fv;
    }
}

// ---------------- Kernel 2: zero-barrier MFMA encoder, fragment-packed B ----------------
// R6 evidence: transaction count, not bytes, is the enc wall. Old B-loads were
// 16 scattered 64B segments per instruction (~5200 TA transactions/wave).
// Fragment-packed B makes every B-load one contiguous 1KB coalesced block.
// Rest identical to R5 (wave-private staging, zero __syncthreads).
#define RB 64
#define KH 256
#define SAP 264   // KH + 8 shorts pad

__global__ __launch_bounds__(256, 2) void enc_mfma(
    const float* __restrict__ state,
    const float* __restrict__ sem,
    const unsigned short* __restrict__ wsbuf,
    const float* __restrict__ ws_b, const float* __restrict__ wz_b,
    const float* __restrict__ wa1_b, const float* __restrict__ wa2_b,
    const float* __restrict__ wb1_b, const float* __restrict__ wb2_w,
    const float* __restrict__ wb2_b,
    const float* __restrict__ shape_out,
    float* __restrict__ q_total,
    float* __restrict__ attn_out)
{
    __shared__ unsigned short sA[RB][SAP];    // staged A half-tile (bf16)
    __shared__ unsigned short sComb[RB][136]; // [relu(C1)|relu(C3)], padded
    __shared__ unsigned short sH[RB][72];     // relu(C4), padded

    int tid  = threadIdx.x;
    int lane = tid & 63;
    int w    = tid >> 6;
    int col  = lane & 15;
    int quad = lane >> 4;
    int r0   = blockIdx.x * RB;
    int rowt = w * 16;

    // fragment-packed bases: each (ks,ct) block is 512 shorts; this lane's slice
    const unsigned short* fS  = wsbuf + OFF_WST  + lane * 8;
    const unsigned short* fB  = wsbuf + OFF_WB1T + lane * 8;
    const unsigned short* fZ  = wsbuf + OFF_WZT  + lane * 8;
    const unsigned short* fA1 = wsbuf + OFF_WA1T + lane * 8;
    const unsigned short* fA2 = wsbuf + OFF_WA2T + lane * 8;

    f32x4 accS[4], accB[4], accZ[4];
    #pragma unroll
    for (int ct = 0; ct < 4; ct++) {
        accS[ct] = (f32x4){0.f,0.f,0.f,0.f};
        accB[ct] = (f32x4){0.f,0.f,0.f,0.f};
        accZ[ct] = (f32x4){0.f,0.f,0.f,0.f};
    }

    // ---- state -> accS (ws), accB (wb1): two K-halves, wave-private staging ----
    #pragma unroll 1
    for (int h = 0; h < 2; h++) {
        int c0 = h * KH;
        #pragma unroll
        for (int b = 0; b < 2; b++) {
            float4 v[8];
            #pragma unroll
            for (int i = 0; i < 8; i++)
                v[i] = *(const float4*)&state[(size_t)(r0 + rowt + b*8 + i) * SD + c0 + lane * 4];
            #pragma unroll
            for (int i = 0; i < 8; i++) {
                uint2 p; p.x = pack2(v[i].x, v[i].y); p.y = pack2(v[i].z, v[i].w);
                *(uint2*)&sA[rowt + b*8 + i][lane * 4] = p;
            }
        }
        #pragma unroll
        for (int ks = 0; ks < 8; ks++) {
            bf16x8 a = *(const bf16x8*)&sA[rowt + col][ks * 32 + quad * 8];
            int fof = (h * 8 + ks) * 4 * 512;
            #pragma unroll
            for (int ct = 0; ct < 4; ct++) {
                bf16x8 bS = *(const bf16x8*)(fS + fof + ct * 512);
                bf16x8 bB = *(const bf16x8*)(fB + fof + ct * 512);
                accS[ct] = MFMA16(a, bS, accS[ct]);
                accB[ct] = MFMA16(a, bB, accB[ct]);
            }
        }
    }

    // ---- sem -> accZ (wz) ----
    #pragma unroll 1
    for (int h = 0; h < 2; h++) {
        int c0 = h * KH;
        #pragma unroll
        for (int b = 0; b < 2; b++) {
            float4 v[8];
            #pragma unroll
            for (int i = 0; i < 8; i++)
                v[i] = *(const float4*)&sem[(size_t)(r0 + rowt + b*8 + i) * SD + c0 + lane * 4];
            #pragma unroll
            for (int i = 0; i < 8; i++) {
                uint2 p; p.x = pack2(v[i].x, v[i].y); p.y = pack2(v[i].z, v[i].w);
                *(uint2*)&sA[rowt + b*8 + i][lane * 4] = p;
            }
        }
        #pragma unroll
        for (int ks = 0; ks < 8; ks++) {
            bf16x8 a = *(const bf16x8*)&sA[rowt + col][ks * 32 + quad * 8];
            int fof = (h * 8 + ks) * 4 * 512;
            #pragma unroll
            for (int ct = 0; ct < 4; ct++) {
                bf16x8 bZ = *(const bf16x8*)(fZ + fof + ct * 512);
                accZ[ct] = MFMA16(a, bZ, accZ[ct]);
            }
        }
    }

    // ---- comb = [relu(C1+ws_b) | relu(C3+wz_b)] (own rows only -> no barrier) ----
    #pragma unroll
    for (int ct = 0; ct < 4; ct++) {
        float bs = ws_b[ct * 16 + col];
        float bz = wz_b[ct * 16 + col];
        #pragma unroll
        for (int reg = 0; reg < 4; reg++) {
            int rr = rowt + quad * 4 + reg;
            sComb[rr][ct * 16 + col]      = f2bf(fmaxf(accS[ct][reg] + bs, 0.f));
            sComb[rr][64 + ct * 16 + col] = f2bf(fmaxf(accZ[ct][reg] + bz, 0.f));
        }
    }

    // ---- bias head: qb = relu(C2+wb1_b) @ wb2_w ----
    float qbv[4];
    #pragma unroll
    for (int reg = 0; reg < 4; reg++) {
        float p = 0.f;
        #pragma unroll
        for (int ct = 0; ct < 4; ct++)
            p += fmaxf(accB[ct][reg] + wb1_b[ct * 16 + col], 0.f) * wb2_w[ct * 16 + col];
        #pragma unroll
        for (int m = 1; m < 16; m <<= 1) p += __shfl_xor(p, m, 64);
        qbv[reg] = p;
    }

    // ---- C4 = comb @ wa1 (own rows) ----
    f32x4 accH[4];
    #pragma unroll
    for (int ct = 0; ct < 4; ct++) accH[ct] = (f32x4){0.f,0.f,0.f,0.f};
    #pragma unroll
    for (int ks = 0; ks < 4; ks++) {
        bf16x8 a = *(const bf16x8*)&sComb[rowt + col][ks * 32 + quad * 8];
        #pragma unroll
        for (int ct = 0; ct < 4; ct++) {
            bf16x8 b = *(const bf16x8*)(fA1 + (ks * 4 + ct) * 512);
            accH[ct] = MFMA16(a, b, accH[ct]);
        }
    }
    #pragma unroll
    for (int ct = 0; ct < 4; ct++) {
        float bh = wa1_b[ct * 16 + col];
        #pragma unroll
        for (int reg = 0; reg < 4; reg++)
            sH[rowt + quad * 4 + reg][ct * 16 + col] = f2bf(fmaxf(accH[ct][reg] + bh, 0.f));
    }

    bf16x8 ha0 = *(const bf16x8*)&sH[rowt + col][quad * 8];
    bf16x8 ha1 = *(const bf16x8*)&sH[rowt + col][32 + quad * 8];

    // ---- pass 1: sum of exp(logits), weighted sum with shape_out ----
    float sAcc[4] = {0.f,0.f,0.f,0.f};
    float wAcc[4] = {0.f,0.f,0.f,0.f};
    for (int nt = 0; nt < 33; nt++) {
        f32x4 acc = (f32x4){0.f,0.f,0.f,0.f};
        acc = MFMA16(ha0, *(const bf16x8*)(fA2 + nt * 1024), acc);
        acc = MFMA16(ha1, *(const bf16x8*)(fA2 + nt * 1024 + 512), acc);
        float lb = wa2_b[nt * 16 + col];
        #pragma unroll
        for (int reg = 0; reg < 4; reg++) {
            float e = __expf(acc[reg] + lb);
            sAcc[reg] += e;
            wAcc[reg] += e * shape_out[(size_t)(r0 + rowt + quad * 4 + reg) * NF + nt * 16 + col];
        }
    }
    float inv[4];
    #pragma unroll
    for (int reg = 0; reg < 4; reg++) {
        float s = sAcc[reg], ww = wAcc[reg];
        #pragma unroll
        for (int m = 1; m < 16; m <<= 1) { s += __shfl_xor(s, m, 64); ww += __shfl_xor(ww, m, 64); }
        inv[reg] = 1.f / s;
        if (col == 0)
            q_total[r0 + rowt + quad * 4 + reg] = ww * inv[reg] + qbv[reg] + wb2_b[0];
    }

    // ---- pass 2: write normalized attention ----
    for (int nt = 0; nt < 33; nt++) {
        f32x4 acc = (f32x4){0.f,0.f,0.f,0.f};
        acc = MFMA16(ha0, *(const bf16x8*)(fA2 + nt * 1024), acc);
        acc = MFMA16(ha1, *(const bf16x8*)(fA2 + nt * 1024 + 512), acc);
        float lb = wa2_b[nt * 16 + col];
        #pragma unroll
        for (int reg = 0; reg < 4; reg++) {
            float e = __expf(acc[reg] + lb);
            attn_out[(size_t)(r0 + rowt + quad * 4 + reg) * NF + nt * 16 + col] = e * inv[reg];
        }
    }
}

extern "C" void kernel_launch(void* const* d_in, const int* in_sizes, int n_in,
                              void* d_out, int out_size, void* d_ws, size_t ws_size,
                              hipStream_t stream) {
    const float* q     = (const float*)d_in[0];
    const float* state = (const float*)d_in[1];
    const float* sem   = (const float*)d_in[2];
    const float* w1_1  = (const float*)d_in[3];
    const float* b1_1  = (const float*)d_in[4];
    const float* w2_1  = (const float*)d_in[5];
    const float* b2_1  = (const float*)d_in[6];
    const float* w3_1  = (const float*)d_in[7];
    const float* b3_1  = (const float*)d_in[8];
    const float* w1_2  = (const float*)d_in[9];
    const float* b1_2  = (const float*)d_in[10];
    const float* w2_2  = (const float*)d_in[11];
    const float* b2_2  = (const float*)d_in[12];
    const float* w3_2  = (const float*)d_in[13];
    const float* b3_2  = (const float*)d_in[14];
    const float* ws_w  = (const float*)d_in[15];
    const float* ws_b  = (const float*)d_in[16];
    const float* wz_w  = (const float*)d_in[17];
    const float* wz_b  = (const float*)d_in[18];
    const float* wa1_w = (const float*)d_in[19];
    const float* wa1_b = (const float*)d_in[20];
    const float* wa2_w = (const float*)d_in[21];
    const float* wa2_b = (const float*)d_in[22];
    const float* wb1_w = (const float*)d_in[23];
    const float* wb1_b = (const float*)d_in[24];
    const float* wb2_w = (const float*)d_in[25];
    const float* wb2_b = (const float*)d_in[26];

    int B = in_sizes[0] / NAG;

    float* out_q    = (float*)d_out;                 // [B]
    float* out_attn = out_q + B;                     // [B, NF]
    float* out_shp  = out_attn + (size_t)B * NF;     // [B, NF]

    unsigned short* wsbuf = (unsigned short*)d_ws;

    prep_kernel<<<(PREP_TOT + 255) / 256, 256, 0, stream>>>(
        ws_w, wb1_w, wz_w, wa1_w, wa2_w, wsbuf);

    shape_kernel<<<B / SROWS, 576, 0, stream>>>(q,
        w1_1, b1_1, w2_1, b2_1, w3_1, b3_1,
        w1_2, b1_2, w2_2, b2_2, w3_2, b3_2,
        out_shp, B);

    enc_mfma<<<B / RB, 256, 0, stream>>>(state, sem, wsbuf,
        ws_b, wz_b, wa1_b, wa2_b, wb1_b, wb2_w, wb2_b,
        out_shp, out_q, out_attn);
}

// Round 8
// 373.819 us; speedup vs baseline: 1.9618x; 1.0013x over previous
//
#include <hip/hip_runtime.h>
#include <cstdint>
#include <cstddef>

#define NAG 32
#define N1C 32
#define N2C 496
#define NF 528
#define HD 64
#define SD 512

typedef __attribute__((ext_vector_type(8))) short bf16x8;
typedef __attribute__((ext_vector_type(4))) float f32x4;
#define MFMA16(a, b, c) __builtin_amdgcn_mfma_f32_16x16x32_bf16(a, b, c, 0, 0, 0)

__device__ __forceinline__ unsigned short f2bf(float f) {
    unsigned int u = __float_as_uint(f);
    u += 0x7fffu + ((u >> 16) & 1u);
    return (unsigned short)(u >> 16);
}
__device__ __forceinline__ unsigned int pack2(float a, float b) {
    return (unsigned int)f2bf(a) | ((unsigned int)f2bf(b) << 16);
}
__device__ __forceinline__ float elu_f(float x) {
    return x > 0.f ? x : (__expf(x) - 1.f);
}

// ---- d_ws layout (ushort/bf16), ALL FRAGMENT-PACKED (R7, proven: enc 121->93us):
//   wsF / wb1F / wzF: [ks(16)][ct(4)][lane(64)][8]  (32768 each)
//   wa1F:             [ks(4)][ct(4)][lane(64)][8]   (8192)
//   wa2F:             [nt(33)][half(2)][lane(64)][8] (33792)
#define OFF_WST   0
#define OFF_WB1T  32768
#define OFF_WZT   65536
#define OFF_WA1T  98304
#define OFF_WA2T  106496
#define PREP_TOT  140288

// ---------------- Kernel 0: weight fragment-pack + bf16 convert ----------------
__global__ __launch_bounds__(256) void prep_kernel(
    const float* __restrict__ ws_w, const float* __restrict__ wb1_w,
    const float* __restrict__ wz_w, const float* __restrict__ wa1_w,
    const float* __restrict__ wa2_w, unsigned short* __restrict__ ws)
{
    int i = blockIdx.x * 256 + threadIdx.x;
    if (i >= PREP_TOT) return;
    float v;
    if (i < OFF_WA1T) {
        int region = i >> 15;            // 0=ws, 1=wb1, 2=wz
        int j = i & 32767;
        int e = j & 7, lane = (j >> 3) & 63, ct = (j >> 9) & 3, ks = j >> 11;
        int n = ct * 16 + (lane & 15);
        int k = ks * 32 + (lane >> 4) * 8 + e;
        const float* src = region == 0 ? ws_w : (region == 1 ? wb1_w : wz_w);
        v = src[k * 64 + n];
    } else if (i < OFF_WA2T) {
        int j = i - OFF_WA1T;
        int e = j & 7, lane = (j >> 3) & 63, ct = (j >> 9) & 3, ks = j >> 11;  // ks 0..3
        int n = ct * 16 + (lane & 15);
        int k = ks * 32 + (lane >> 4) * 8 + e;   // 0..127
        v = wa1_w[k * 64 + n];
    } else {
        int j = i - OFF_WA2T;
        int e = j & 7, lane = (j >> 3) & 63, hh = (j >> 9) & 1, nt = j >> 10;  // nt 0..32
        int n = nt * 16 + (lane & 15);
        int k = hh * 32 + (lane >> 4) * 8 + e;   // 0..63
        v = wa2_w[k * NF + n];
    }
    ws[i] = f2bf(v);
}

// ---------------- Kernel 1: fused enc + shape (single compute kernel) ----------------
// R7 accounting: controllable time = enc 93us (memory-bound, VALU 11%) + shape 76us
// (VALU-bound) run SERIALLY. Fuse shape into enc the R0-PROVEN way (thread->function,
// weights in registers once per fn — NOT R6's divergent in-loop gathers): 256 threads
// each compute 2-3 functions x 64 rows from an LDS q-tile, write shape_out coalesced,
// one barrier, then the unchanged R7 enc body. pass 1's shape_out read becomes an
// L2 hit (same block wrote it). Shape VALU fills enc's idle VALU slots (2 blocks/CU).
#define RB 64
#define KH 256
#define SAP 264   // KH + 8 shorts pad (row stride 528B -> banks spread)

__global__ __launch_bounds__(256, 2) void enc_mfma(
    const float* __restrict__ q,
    const float* __restrict__ state,
    const float* __restrict__ sem,
    const unsigned short* __restrict__ wsbuf,
    const float* __restrict__ ws_b, const float* __restrict__ wz_b,
    const float* __restrict__ wa1_b, const float* __restrict__ wa2_b,
    const float* __restrict__ wb1_b, const float* __restrict__ wb2_w,
    const float* __restrict__ wb2_b,
    const float* __restrict__ w1_1, const float* __restrict__ b1_1,
    const float* __restrict__ w2_1, const float* __restrict__ b2_1,
    const float* __restrict__ w3_1, const float* __restrict__ b3_1,
    const float* __restrict__ w1_2, const float* __restrict__ b1_2,
    const float* __restrict__ w2_2, const float* __restrict__ b2_2,
    const float* __restrict__ w3_2, const float* __restrict__ b3_2,
    float* __restrict__ shape_out,
    float* __restrict__ q_total,
    float* __restrict__ attn_out)
{
    __shared__ unsigned short sA[RB][SAP];    // staged A half-tile (bf16)
    __shared__ unsigned short sComb[RB][136]; // [relu(C1)|relu(C3)], padded
    __shared__ unsigned short sH[RB][72];     // relu(C4), padded
    __shared__ float qs[RB][36];              // q tile f32 (padded)

    int tid  = threadIdx.x;
    int lane = tid & 63;
    int w    = tid >> 6;
    int col  = lane & 15;
    int quad = lane >> 4;
    int r0   = blockIdx.x * RB;
    int rowt = w * 16;

    // ---- stage q tile [64][32] (8KB, coalesced: 8 floats per thread) ----
    {
        int idx = tid * 8;           // 0..2047
        int qr  = idx >> 5;          // 0..63
        int qc  = idx & 31;          // 0,8,16,24
        float4 v0 = *(const float4*)&q[(size_t)(r0 + qr) * NAG + qc];
        float4 v1 = *(const float4*)&q[(size_t)(r0 + qr) * NAG + qc + 4];
        qs[qr][qc + 0] = v0.x; qs[qr][qc + 1] = v0.y;
        qs[qr][qc + 2] = v0.z; qs[qr][qc + 3] = v0.w;
        qs[qr][qc + 4] = v1.x; qs[qr][qc + 5] = v1.y;
        qs[qr][qc + 6] = v1.z; qs[qr][qc + 7] = v1.w;
    }
    __syncthreads();

    // ---- shape phase: thread handles fns {tid, tid+256, tid+512<528} ----
    for (int fi = 0; fi < 3; fi++) {
        int f = tid + fi * 256;
        if (f >= NF) break;
        float w1a[8], w1b[8], b1v[8], w2v[32], b2v[4], w3v[4], b3v;
        int pi, pj;
        if (f < N1C) {
            int n = f; pi = n; pj = n;
            #pragma unroll
            for (int k = 0; k < 8; k++) { w1a[k] = fabsf(w1_1[n*8+k]); w1b[k] = 0.f; b1v[k] = b1_1[n*8+k]; }
            #pragma unroll
            for (int t = 0; t < 32; t++) w2v[t] = fabsf(w2_1[n*32+t]);
            #pragma unroll
            for (int j = 0; j < 4; j++) { b2v[j] = b2_1[n*4+j]; w3v[j] = fabsf(w3_1[n*4+j]); }
            b3v = b3_1[n];
        } else {
            int n = f - N1C;
            int p = n, ii = 0, c = NAG - 1;
            while (p >= c) { p -= c; c--; ii++; }
            pi = ii; pj = ii + 1 + p;
            #pragma unroll
            for (int k = 0; k < 8; k++) { w1a[k] = fabsf(w1_2[n*16+k]); w1b[k] = fabsf(w1_2[n*16+8+k]); b1v[k] = b1_2[n*8+k]; }
            #pragma unroll
            for (int t = 0; t < 32; t++) w2v[t] = fabsf(w2_2[n*32+t]);
            #pragma unroll
            for (int j = 0; j < 4; j++) { b2v[j] = b2_2[n*4+j]; w3v[j] = fabsf(w3_2[n*4+j]); }
            b3v = b3_2[n];
        }
        #pragma unroll 4
        for (int rr = 0; rr < RB; rr++) {
            float qi = qs[rr][pi];
            float qj = qs[rr][pj];
            float h1[8];
            #pragma unroll
            for (int k = 0; k < 8; k++) h1[k] = elu_f(w1a[k]*qi + w1b[k]*qj + b1v[k]);
            float h2[4];
            #pragma unroll
            for (int j = 0; j < 4; j++) {
                float a = b2v[j];
                #pragma unroll
                for (int k = 0; k < 8; k++) a += h1[k] * w2v[k*4 + j];
                h2[j] = elu_f(a);
            }
            float fv = b3v;
            #pragma unroll
            for (int j = 0; j < 4; j++) fv += h2[j] * w3v[j];
            shape_out[(size_t)(r0 + rr) * NF + f] = fv;
        }
    }
    // barrier: shape stores drained (vmcnt(0)) before any wave's pass 1 reads them
    __syncthreads();

    // fragment-packed bases: each (ks,ct) block is 512 shorts; this lane's slice
    const unsigned short* fS  = wsbuf + OFF_WST  + lane * 8;
    const unsigned short* fB  = wsbuf + OFF_WB1T + lane * 8;
    const unsigned short* fZ  = wsbuf + OFF_WZT  + lane * 8;
    const unsigned short* fA1 = wsbuf + OFF_WA1T + lane * 8;
    const unsigned short* fA2 = wsbuf + OFF_WA2T + lane * 8;

    f32x4 accS[4], accB[4], accZ[4];
    #pragma unroll
    for (int ct = 0; ct < 4; ct++) {
        accS[ct] = (f32x4){0.f,0.f,0.f,0.f};
        accB[ct] = (f32x4){0.f,0.f,0.f,0.f};
        accZ[ct] = (f32x4){0.f,0.f,0.f,0.f};
    }

    // ---- state -> accS (ws), accB (wb1): two K-halves, wave-private staging ----
    #pragma unroll 1
    for (int h = 0; h < 2; h++) {
        int c0 = h * KH;
        #pragma unroll
        for (int b = 0; b < 2; b++) {
            float4 v[8];
            #pragma unroll
            for (int i = 0; i < 8; i++)
                v[i] = *(const float4*)&state[(size_t)(r0 + rowt + b*8 + i) * SD + c0 + lane * 4];
            #pragma unroll
            for (int i = 0; i < 8; i++) {
                uint2 p; p.x = pack2(v[i].x, v[i].y); p.y = pack2(v[i].z, v[i].w);
                *(uint2*)&sA[rowt + b*8 + i][lane * 4] = p;
            }
        }
        #pragma unroll
        for (int ks = 0; ks < 8; ks++) {
            bf16x8 a = *(const bf16x8*)&sA[rowt + col][ks * 32 + quad * 8];
            int fof = (h * 8 + ks) * 4 * 512;
            #pragma unroll
            for (int ct = 0; ct < 4; ct++) {
                bf16x8 bS = *(const bf16x8*)(fS + fof + ct * 512);
                bf16x8 bB = *(const bf16x8*)(fB + fof + ct * 512);
                accS[ct] = MFMA16(a, bS, accS[ct]);
                accB[ct] = MFMA16(a, bB, accB[ct]);
            }
        }
    }

    // ---- sem -> accZ (wz) ----
    #pragma unroll 1
    for (int h = 0; h < 2; h++) {
        int c0 = h * KH;
        #pragma unroll
        for (int b = 0; b < 2; b++) {
            float4 v[8];
            #pragma unroll
            for (int i = 0; i < 8; i++)
                v[i] = *(const float4*)&sem[(size_t)(r0 + rowt + b*8 + i) * SD + c0 + lane * 4];
            #pragma unroll
            for (int i = 0; i < 8; i++) {
                uint2 p; p.x = pack2(v[i].x, v[i].y); p.y = pack2(v[i].z, v[i].w);
                *(uint2*)&sA[rowt + b*8 + i][lane * 4] = p;
            }
        }
        #pragma unroll
        for (int ks = 0; ks < 8; ks++) {
            bf16x8 a = *(const bf16x8*)&sA[rowt + col][ks * 32 + quad * 8];
            int fof = (h * 8 + ks) * 4 * 512;
            #pragma unroll
            for (int ct = 0; ct < 4; ct++) {
                bf16x8 bZ = *(const bf16x8*)(fZ + fof + ct * 512);
                accZ[ct] = MFMA16(a, bZ, accZ[ct]);
            }
        }
    }

    // ---- comb = [relu(C1+ws_b) | relu(C3+wz_b)] (own rows only -> no barrier) ----
    #pragma unroll
    for (int ct = 0; ct < 4; ct++) {
        float bs = ws_b[ct * 16 + col];
        float bz = wz_b[ct * 16 + col];
        #pragma unroll
        for (int reg = 0; reg < 4; reg++) {
            int rr = rowt + quad * 4 + reg;
            sComb[rr][ct * 16 + col]      = f2bf(fmaxf(accS[ct][reg] + bs, 0.f));
            sComb[rr][64 + ct * 16 + col] = f2bf(fmaxf(accZ[ct][reg] + bz, 0.f));
        }
    }

    // ---- bias head: qb = relu(C2+wb1_b) @ wb2_w ----
    float qbv[4];
    #pragma unroll
    for (int reg = 0; reg < 4; reg++) {
        float p = 0.f;
        #pragma unroll
        for (int ct = 0; ct < 4; ct++)
            p += fmaxf(accB[ct][reg] + wb1_b[ct * 16 + col], 0.f) * wb2_w[ct * 16 + col];
        #pragma unroll
        for (int m = 1; m < 16; m <<= 1) p += __shfl_xor(p, m, 64);
        qbv[reg] = p;
    }

    // ---- C4 = comb @ wa1 (own rows) ----
    f32x4 accH[4];
    #pragma unroll
    for (int ct = 0; ct < 4; ct++) accH[ct] = (f32x4){0.f,0.f,0.f,0.f};
    #pragma unroll
    for (int ks = 0; ks < 4; ks++) {
        bf16x8 a = *(const bf16x8*)&sComb[rowt + col][ks * 32 + quad * 8];
        #pragma unroll
        for (int ct = 0; ct < 4; ct++) {
            bf16x8 b = *(const bf16x8*)(fA1 + (ks * 4 + ct) * 512);
            accH[ct] = MFMA16(a, b, accH[ct]);
        }
    }
    #pragma unroll
    for (int ct = 0; ct < 4; ct++) {
        float bh = wa1_b[ct * 16 + col];
        #pragma unroll
        for (int reg = 0; reg < 4; reg++)
            sH[rowt + quad * 4 + reg][ct * 16 + col] = f2bf(fmaxf(accH[ct][reg] + bh, 0.f));
    }

    bf16x8 ha0 = *(const bf16x8*)&sH[rowt + col][quad * 8];
    bf16x8 ha1 = *(const bf16x8*)&sH[rowt + col][32 + quad * 8];

    // ---- pass 1: sum of exp(logits), weighted sum with shape_out (L2-hot) ----
    float sAcc[4] = {0.f,0.f,0.f,0.f};
    float wAcc[4] = {0.f,0.f,0.f,0.f};
    for (int nt = 0; nt < 33; nt++) {
        f32x4 acc = (f32x4){0.f,0.f,0.f,0.f};
        acc = MFMA16(ha0, *(const bf16x8*)(fA2 + nt * 1024), acc);
        acc = MFMA16(ha1, *(const bf16x8*)(fA2 + nt * 1024 + 512), acc);
        float lb = wa2_b[nt * 16 + col];
        #pragma unroll
        for (int reg = 0; reg < 4; reg++) {
            float e = __expf(acc[reg] + lb);
            sAcc[reg] += e;
            wAcc[reg] += e * shape_out[(size_t)(r0 + rowt + quad * 4 + reg) * NF + nt * 16 + col];
        }
    }
    float inv[4];
    #pragma unroll
    for (int reg = 0; reg < 4; reg++) {
        float s = sAcc[reg], ww = wAcc[reg];
        #pragma unroll
        for (int m = 1; m < 16; m <<= 1) { s += __shfl_xor(s, m, 64); ww += __shfl_xor(ww, m, 64); }
        inv[reg] = 1.f / s;
        if (col == 0)
            q_total[r0 + rowt + quad * 4 + reg] = ww * inv[reg] + qbv[reg] + wb2_b[0];
    }

    // ---- pass 2: write normalized attention ----
    for (int nt = 0; nt < 33; nt++) {
        f32x4 acc = (f32x4){0.f,0.f,0.f,0.f};
        acc = MFMA16(ha0, *(const bf16x8*)(fA2 + nt * 1024), acc);
        acc = MFMA16(ha1, *(const bf16x8*)(fA2 + nt * 1024 + 512), acc);
        float lb = wa2_b[nt * 16 + col];
        #pragma unroll
        for (int reg = 0; reg < 4; reg++) {
            float e = __expf(acc[reg] + lb);
            attn_out[(size_t)(r0 + rowt + quad * 4 + reg) * NF + nt * 16 + col] = e * inv[reg];
        }
    }
}

extern "C" void kernel_launch(void* const* d_in, const int* in_sizes, int n_in,
                              void* d_out, int out_size, void* d_ws, size_t ws_size,
                              hipStream_t stream) {
    const float* q     = (const float*)d_in[0];
    const float* state = (const float*)d_in[1];
    const float* sem   = (const float*)d_in[2];
    const float* w1_1  = (const float*)d_in[3];
    const float* b1_1  = (const float*)d_in[4];
    const float* w2_1  = (const float*)d_in[5];
    const float* b2_1  = (const float*)d_in[6];
    const float* w3_1  = (const float*)d_in[7];
    const float* b3_1  = (const float*)d_in[8];
    const float* w1_2  = (const float*)d_in[9];
    const float* b1_2  = (const float*)d_in[10];
    const float* w2_2  = (const float*)d_in[11];
    const float* b2_2  = (const float*)d_in[12];
    const float* w3_2  = (const float*)d_in[13];
    const float* b3_2  = (const float*)d_in[14];
    const float* ws_w  = (const float*)d_in[15];
    const float* ws_b  = (const float*)d_in[16];
    const float* wz_w  = (const float*)d_in[17];
    const float* wz_b  = (const float*)d_in[18];
    const float* wa1_w = (const float*)d_in[19];
    const float* wa1_b = (const float*)d_in[20];
    const float* wa2_w = (const float*)d_in[21];
    const float* wa2_b = (const float*)d_in[22];
    const float* wb1_w = (const float*)d_in[23];
    const float* wb1_b = (const float*)d_in[24];
    const float* wb2_w = (const float*)d_in[25];
    const float* wb2_b = (const float*)d_in[26];

    int B = in_sizes[0] / NAG;

    float* out_q    = (float*)d_out;                 // [B]
    float* out_attn = out_q + B;                     // [B, NF]
    float* out_shp  = out_attn + (size_t)B * NF;     // [B, NF]

    unsigned short* wsbuf = (unsigned short*)d_ws;

    prep_kernel<<<(PREP_TOT + 255) / 256, 256, 0, stream>>>(
        ws_w, wb1_w, wz_w, wa1_w, wa2_w, wsbuf);

    enc_mfma<<<B / RB, 256, 0, stream>>>(q, state, sem, wsbuf,
        ws_b, wz_b, wa1_b, wa2_b, wb1_b, wb2_w, wb2_b,
        w1_1, b1_1, w2_1, b2_1, w3_1, b3_1,
        w1_2, b1_2, w2_2, b2_2, w3_2, b3_2,
        out_shp, out_q, out_attn);
}